// Round 3
// baseline (380.216 us; speedup 1.0000x reference)
//
#include <hip/hip_runtime.h>
#include <math.h>

#define NBINS 15
#define NCLS 100
#define ECE_EPS 1e-5f

// Kernel A: one wave (64-thread block) stages 64 rows (25.6 KB) into LDS with
// coalesced global_load_lds (16B/lane, 1KB/instr), then lane L processes row L
// entirely from LDS. Output: 100-entry argmax histogram + acc sums.
__global__ __launch_bounds__(64) void ece_hist(const float* __restrict__ logits,
                                               const int* __restrict__ labels,
                                               int* __restrict__ g_cnt,
                                               float* __restrict__ g_acc,
                                               int n_rows) {
    __shared__ float s_rows[64 * NCLS];   // 25.6 KB staging: linear copy of the chunk
    __shared__ int   s_cnt[NCLS];
    __shared__ float s_accs[NCLS];

    const int lane = threadIdx.x;          // 0..63, single wave per block
    #pragma unroll
    for (int i = lane; i < NCLS; i += 64) { s_cnt[i] = 0; s_accs[i] = 0.0f; }

    const int n_chunks = n_rows >> 6;      // 64 rows per chunk
    for (int chunk = blockIdx.x; chunk < n_chunks; chunk += gridDim.x) {
        const float* gbase = logits + (size_t)chunk * (64 * NCLS);
        // ---- stage 1600 float4 = 25.6 KB, coalesced; LDS dst wave-uniform,
        //      data lands at dst + lane*16 -> exact linear copy ----
        #pragma unroll
        for (int j = 0; j < 25; ++j) {
            __builtin_amdgcn_global_load_lds(
                (const __attribute__((address_space(1))) void*)(gbase + (size_t)(j * 64 + lane) * 4),
                (__attribute__((address_space(3))) void*)(&s_rows[j * 256]),
                16, 0, 0);
        }
        const int lab = labels[chunk * 64 + lane];   // overlaps with LDS fill
        __builtin_amdgcn_s_waitcnt(0);               // drain vmcnt (LDS writes done)

        // ---- row `lane` lives at s_rows[lane*100 .. +99], 16B-aligned ----
        const float4* __restrict__ rp = (const float4*)&s_rows[lane * NCLS];
        float4 v[25];
        #pragma unroll
        for (int j = 0; j < 25; ++j) v[j] = rp[j];

        // max/argmax, first-occurrence tie-break (matches jnp.argmax)
        float m = -INFINITY; int mi = 0;
        #pragma unroll
        for (int j = 0; j < 25; ++j) {
            if (v[j].x > m) { m = v[j].x; mi = 4 * j;     }
            if (v[j].y > m) { m = v[j].y; mi = 4 * j + 1; }
            if (v[j].z > m) { m = v[j].z; mi = 4 * j + 2; }
            if (v[j].w > m) { m = v[j].w; mi = 4 * j + 3; }
        }
        // sum exp(x - m), 4 partial sums for ILP
        float s0 = 0.0f, s1 = 0.0f, s2 = 0.0f, s3 = 0.0f;
        #pragma unroll
        for (int j = 0; j < 25; ++j) {
            s0 += __expf(v[j].x - m);
            s1 += __expf(v[j].y - m);
            s2 += __expf(v[j].z - m);
            s3 += __expf(v[j].w - m);
        }
        const float pred = -__logf((s0 + s1) + (s2 + s3));  // max of log_softmax

        atomicAdd(&s_cnt[mi], 1);
        if (pred == (float)lab) atomicAdd(&s_accs[mi], 1.0f);  // faithful; ~never taken
    }

    // ---- tail rows (n_rows % 64), block 0 only; scattered but tiny/rare ----
    const int tail_start = n_chunks << 6;
    if (blockIdx.x == 0 && tail_start + lane < n_rows) {
        const float* row = logits + (size_t)(tail_start + lane) * NCLS;
        float m = -INFINITY; int mi = 0;
        for (int c = 0; c < NCLS; ++c) { const float x = row[c]; if (x > m) { m = x; mi = c; } }
        float s = 0.0f;
        for (int c = 0; c < NCLS; ++c) s += __expf(row[c] - m);
        const float pred = -__logf(s);
        atomicAdd(&s_cnt[mi], 1);
        if (pred == (float)labels[tail_start + lane]) atomicAdd(&s_accs[mi], 1.0f);
    }

    // single wave per block: LDS atomics above are wave-ordered; no barrier needed
    #pragma unroll
    for (int i = lane; i < NCLS; i += 64) {
        if (s_cnt[i])          atomicAdd(&g_cnt[i], s_cnt[i]);
        if (s_accs[i] != 0.0f) atomicAdd(&g_acc[i], s_accs[i]);
    }
}

// Kernel B: fold the 100-entry histogram into the 15-bin sums and the final scalar.
// coeff(c,b) = softmax_b( -(c - anchor_b)^2 / 0.01 ), identical math to reference.
__global__ void ece_final(const int* __restrict__ g_cnt,
                          const float* __restrict__ g_acc,
                          float* __restrict__ out) {
    __shared__ float s_bins[3 * NBINS];
    const int tid = threadIdx.x;
    if (tid < 3 * NBINS) s_bins[tid] = 0.0f;
    __syncthreads();

    if (tid < NCLS) {
        const float cnt  = (float)g_cnt[tid];
        const float accv = g_acc[tid];
        const float conf = (float)tid;
        float diff[NBINS];
        float dm = -INFINITY;
        #pragma unroll
        for (int b = 0; b < NBINS; ++b) {
            const float a = (float)(2 * b + 1) * (1.0f / 30.0f);
            const float d = conf - a;
            diff[b] = -(d * d) * 100.0f;
            dm = fmaxf(dm, diff[b]);
        }
        float es = 0.0f;
        float e[NBINS];
        #pragma unroll
        for (int b = 0; b < NBINS; ++b) { e[b] = __expf(diff[b] - dm); es += e[b]; }
        const float inv = 1.0f / es;
        #pragma unroll
        for (int b = 0; b < NBINS; ++b) {
            const float coeff = e[b] * inv;
            atomicAdd(&s_bins[b],             cnt * coeff);
            atomicAdd(&s_bins[NBINS + b],     conf * cnt * coeff);
            atomicAdd(&s_bins[2 * NBINS + b], accv * coeff);
        }
    }
    __syncthreads();

    if (tid == 0) {
        float total = 0.0f;
        #pragma unroll
        for (int b = 0; b < NBINS; ++b) total += fabsf(s_bins[b]);
        const float invw = 1.0f / fmaxf(total, ECE_EPS);
        float ece = 0.0f;
        #pragma unroll
        for (int b = 0; b < NBINS; ++b) {
            const float sc = s_bins[b];
            const float denom = fmaxf(sc, ECE_EPS);
            const float bc = s_bins[NBINS + b] / denom;
            const float ba = s_bins[2 * NBINS + b] / denom;
            const float d  = bc - ba;
            ece += d * d * (sc * invw);
        }
        out[0] = sqrtf(ece);
    }
}

extern "C" void kernel_launch(void* const* d_in, const int* in_sizes, int n_in,
                              void* d_out, int out_size, void* d_ws, size_t ws_size,
                              hipStream_t stream) {
    const float* logits = (const float*)d_in[0];
    const int*   labels = (const int*)d_in[1];
    int*   g_cnt = (int*)d_ws;
    float* g_acc = (float*)((char*)d_ws + NCLS * sizeof(int));
    float* outp  = (float*)d_out;
    const int n_rows = in_sizes[1];   // labels element count = N

    hipMemsetAsync(d_ws, 0, NCLS * (sizeof(int) + sizeof(float)), stream);
    // 2048 single-wave blocks; N=524288 -> 8192 chunks -> 4 chunks/block.
    ece_hist<<<2048, 64, 0, stream>>>(logits, labels, g_cnt, g_acc, n_rows);
    ece_final<<<1, 128, 0, stream>>>(g_cnt, g_acc, outp);
}